// Round 4
// baseline (5038.853 us; speedup 1.0000x reference)
//
#include <hip/hip_runtime.h>
#include <hip/hip_bf16.h>

// CGCNN: 3x CGConv + projection + mean-pool + 2-layer MLP.
// Round 4: CSR dst-major aggregation (no float atomics); bf16 node
// transforms Pb (102 MB, L3-resident); bf16 edge transforms Eb computed in
// CSR order, CHUNKED (8 node-chunks, 105 MB buffer) to fit workspace.
//   f = P_fd[dst] + P_fs[src] + E_f[e]   (bias folded into E_f)
//   msg = sigmoid(f) * softplus(s); accumulate in registers per dst wave.

#define N_NODES 100000
#define N_EDGES 1600000
#define HID 128
#define SCAN_BLOCKS 391        // ceil(100000/256)
#define NCHUNK 8
#define NODES_PER_CHUNK 12500  // N_NODES / NCHUNK
#define CHUNK_EDGE_CAP 204800  // mean 200k + 11 sigma
#define CHUNK_BLOCKS (CHUNK_EDGE_CAP / 64)

typedef unsigned int uint;

__device__ inline float bflo(uint u) { return __uint_as_float(u << 16); }
__device__ inline float bfhi(uint u) { return __uint_as_float(u & 0xffff0000u); }
__device__ inline uint pack_bf16_2(float a, float b) {
  uint ua = __float_as_uint(a), ub = __float_as_uint(b);
  ua = (ua + 0x7fffu + ((ua >> 16) & 1u)) >> 16;
  ub = (ub + 0x7fffu + ((ub >> 16) & 1u)) >> 16;
  return ua | (ub << 16);
}
__device__ inline float sigmoidf_(float x) {
  return __builtin_amdgcn_rcpf(1.f + __expf(-x));
}
__device__ inline float softplusf_(float x) {
  return fmaxf(x, 0.f) + __logf(1.f + __expf(-fabsf(x)));
}

// ---------------- CSR build ----------------
__global__ __launch_bounds__(256) void hist_k(const int* __restrict__ ei,
                                              int* __restrict__ deg) {
  int e = blockIdx.x * 256 + threadIdx.x;
  if (e >= N_EDGES) return;
  atomicAdd(&deg[ei[N_EDGES + e]], 1);
}

__global__ __launch_bounds__(256) void scan1_k(const int* __restrict__ deg,
                                               int* __restrict__ rowptr,
                                               int* __restrict__ bsums) {
  __shared__ int s[256];
  int i = blockIdx.x * 256 + threadIdx.x;
  int v = (i < N_NODES) ? deg[i] : 0;
  s[threadIdx.x] = v;
  __syncthreads();
  for (int off = 1; off < 256; off <<= 1) {
    int t = (threadIdx.x >= off) ? s[threadIdx.x - off] : 0;
    __syncthreads();
    s[threadIdx.x] += t;
    __syncthreads();
  }
  if (i < N_NODES) rowptr[i] = s[threadIdx.x] - v;  // exclusive
  if (threadIdx.x == 255) bsums[blockIdx.x] = s[255];
}

__global__ __launch_bounds__(512) void scan2_k(int* __restrict__ bsums) {
  __shared__ int s[512];
  int t = threadIdx.x;
  int v = (t < SCAN_BLOCKS) ? bsums[t] : 0;
  s[t] = v;
  __syncthreads();
  for (int off = 1; off < 512; off <<= 1) {
    int x = (t >= off) ? s[t - off] : 0;
    __syncthreads();
    s[t] += x;
    __syncthreads();
  }
  if (t < SCAN_BLOCKS) bsums[t] = s[t] - v;  // exclusive
}

__global__ __launch_bounds__(256) void scan3_k(int* __restrict__ rowptr,
                                               const int* __restrict__ bsums,
                                               int* __restrict__ cur) {
  int i = blockIdx.x * 256 + threadIdx.x;
  if (i < N_NODES) {
    int r = rowptr[i] + bsums[blockIdx.x];
    rowptr[i] = r;
    cur[i] = r;
  }
  if (i == 0) rowptr[N_NODES] = N_EDGES;
}

__global__ __launch_bounds__(256) void scatter_k(const int* __restrict__ ei,
                                                 int* __restrict__ cur,
                                                 uint2* __restrict__ csr) {
  int e = blockIdx.x * 256 + threadIdx.x;
  if (e >= N_EDGES) return;
  int d = ei[N_EDGES + e];
  int pos = atomicAdd(&cur[d], 1);
  csr[pos] = make_uint2((uint)ei[e], (uint)e);
}

// ---------------- conv1 (channels=3) ----------------
__global__ __launch_bounds__(256) void conv1_edge(
    const float* __restrict__ x, const int* __restrict__ ei,
    const float* __restrict__ ea,
    const float* __restrict__ Wf, const float* __restrict__ bf,
    const float* __restrict__ Ws, const float* __restrict__ bs,
    float* __restrict__ agg1) {
  int e = blockIdx.x * 256 + threadIdx.x;
  if (e >= N_EDGES) return;
  int src = ei[e], dst = ei[N_EDGES + e];
  float z[38];
#pragma unroll
  for (int k = 0; k < 3; ++k) z[k] = x[dst * 3 + k];
#pragma unroll
  for (int k = 0; k < 3; ++k) z[3 + k] = x[src * 3 + k];
  const float* er = ea + (long long)e * 32;
#pragma unroll
  for (int k = 0; k < 32; ++k) z[6 + k] = er[k];
#pragma unroll
  for (int c = 0; c < 3; ++c) {
    float f = bf[c], s = bs[c];
#pragma unroll
    for (int k = 0; k < 38; ++k) {
      f = fmaf(z[k], Wf[k * 3 + c], f);
      s = fmaf(z[k], Ws[k * 3 + c], s);
    }
    atomicAdd(&agg1[dst * 3 + c], sigmoidf_(f) * softplusf_(s));
  }
}

// ---------------- projection: h = relu((x+agg1) @ Wp + bp) ----------------
__global__ __launch_bounds__(256) void proj_kernel(
    const float* __restrict__ x, const float* __restrict__ agg1,
    const float* __restrict__ Wp, const float* __restrict__ bp,
    float* __restrict__ h) {
  long long i = (long long)blockIdx.x * 256 + threadIdx.x;
  if (i >= (long long)N_NODES * HID) return;
  int n = (int)(i >> 7), j = (int)(i & 127);
  float v0 = x[n * 3 + 0] + agg1[n * 3 + 0];
  float v1 = x[n * 3 + 1] + agg1[n * 3 + 1];
  float v2 = x[n * 3 + 2] + agg1[n * 3 + 2];
  float acc = bp[j];
  acc = fmaf(v0, Wp[0 * HID + j], acc);
  acc = fmaf(v1, Wp[1 * HID + j], acc);
  acc = fmaf(v2, Wp[2 * HID + j], acc);
  h[i] = fmaxf(acc, 0.f);
}

// ---------------- node transform GEMM -> bf16 Pb ----------------
// Pb[n] (512 bf16): [ f_dst(128) | s_dst(128) | f_src(128) | s_src(128) ]
#define BM 64
#define BK 32
__global__ __launch_bounds__(256) void node_gemm(
    const float* __restrict__ h, const float* __restrict__ Wf,
    const float* __restrict__ Ws, uint* __restrict__ Pb) {
  __shared__ float As[BK][BM + 4];
  __shared__ float Bs[BK][BM + 4];
  int jblk = blockIdx.y;
  int sec = jblk >> 1;
  int colbase = (jblk & 1) * 64;
  const float* W = (sec == 0 || sec == 2) ? Wf : Ws;
  int rowoff = (sec >= 2) ? 128 : 0;
  int m0 = blockIdx.x * BM;
  int tid = threadIdx.x;
  int tx = tid & 15, ty = tid >> 4;
  float acc[4][4] = {};
  for (int k0 = 0; k0 < 128; k0 += BK) {
#pragma unroll
    for (int i = 0; i < 2; ++i) {
      int f = tid + i * 256;
      int r = f >> 3, c4 = (f & 7) * 4;
      float4 v = {0.f, 0.f, 0.f, 0.f};
      int row = m0 + r;
      if (row < N_NODES)
        v = *(const float4*)&h[(long long)row * 128 + k0 + c4];
      As[c4 + 0][r] = v.x; As[c4 + 1][r] = v.y;
      As[c4 + 2][r] = v.z; As[c4 + 3][r] = v.w;
    }
#pragma unroll
    for (int i = 0; i < 2; ++i) {
      int f = tid + i * 256;
      int r = f >> 4, c4 = (f & 15) * 4;
      float4 v = *(const float4*)&W[(long long)(k0 + r + rowoff) * 128 + colbase + c4];
      *(float4*)&Bs[r][c4] = v;
    }
    __syncthreads();
#pragma unroll
    for (int k = 0; k < BK; ++k) {
      float4 a = *(const float4*)&As[k][ty * 4];
      float4 b = *(const float4*)&Bs[k][tx * 4];
      float av[4] = {a.x, a.y, a.z, a.w};
      float bv[4] = {b.x, b.y, b.z, b.w};
#pragma unroll
      for (int i = 0; i < 4; ++i)
#pragma unroll
        for (int j = 0; j < 4; ++j)
          acc[i][j] = fmaf(av[i], bv[j], acc[i][j]);
    }
    __syncthreads();
  }
#pragma unroll
  for (int i = 0; i < 4; ++i) {
    int row = m0 + ty * 4 + i;
    if (row < N_NODES) {
      uint2 o;
      o.x = pack_bf16_2(acc[i][0], acc[i][1]);
      o.y = pack_bf16_2(acc[i][2], acc[i][3]);
      *(uint2*)&Pb[(long long)row * 256 + jblk * 32 + tx * 2] = o;
    }
  }
}

// ------- edge transform GEMM (chunked, CSR order) -> bf16 Eb -------
// Eb[pos-chunkStart] (256 bf16): [ f_e+bf (128) | s_e+bs (128) ]
__global__ __launch_bounds__(256) void egemm_c(
    const float* __restrict__ ea, const uint2* __restrict__ csr,
    const int* __restrict__ rowptr,
    const float* __restrict__ Wf, const float* __restrict__ Ws,
    const float* __restrict__ bf, const float* __restrict__ bs,
    int nodeBase, uint* __restrict__ Eb) {
  __shared__ float As[BK][BM + 4];
  __shared__ float Bs[BK][BM + 4];
  __shared__ int eids[64];
  int chunkStart = rowptr[nodeBase];
  int chunkEnd = rowptr[nodeBase + NODES_PER_CHUNK];
  int pos0 = chunkStart + blockIdx.x * 64;
  if (pos0 >= chunkEnd) return;
  int jblk = blockIdx.y;  // 0..3
  const float* W = (jblk < 2) ? Wf : Ws;
  const float* bias = (jblk < 2) ? bf : bs;
  int wcolbase = (jblk & 1) * 64;
  int tid = threadIdx.x;
  int tx = tid & 15, ty = tid >> 4;
  if (tid < 64) {
    int p = pos0 + tid;
    eids[tid] = (int)csr[(p < chunkEnd) ? p : chunkStart].y;
  }
  __syncthreads();
  float acc[4][4] = {};
#pragma unroll
  for (int i = 0; i < 2; ++i) {
    int f = tid + i * 256;
    int r = f >> 3, c4 = (f & 7) * 4;
    float4 v = *(const float4*)&ea[(long long)eids[r] * 32 + c4];
    As[c4 + 0][r] = v.x; As[c4 + 1][r] = v.y;
    As[c4 + 2][r] = v.z; As[c4 + 3][r] = v.w;
  }
#pragma unroll
  for (int i = 0; i < 2; ++i) {
    int f = tid + i * 256;
    int r = f >> 4, c4 = (f & 15) * 4;
    float4 v = *(const float4*)&W[(long long)(256 + r) * 128 + wcolbase + c4];
    *(float4*)&Bs[r][c4] = v;
  }
  __syncthreads();
#pragma unroll
  for (int k = 0; k < BK; ++k) {
    float4 a = *(const float4*)&As[k][ty * 4];
    float4 b = *(const float4*)&Bs[k][tx * 4];
    float av[4] = {a.x, a.y, a.z, a.w};
    float bv[4] = {b.x, b.y, b.z, b.w};
#pragma unroll
    for (int i = 0; i < 4; ++i)
#pragma unroll
      for (int j = 0; j < 4; ++j)
        acc[i][j] = fmaf(av[i], bv[j], acc[i][j]);
  }
  float b0 = bias[wcolbase + tx * 4 + 0];
  float b1 = bias[wcolbase + tx * 4 + 1];
  float b2 = bias[wcolbase + tx * 4 + 2];
  float b3 = bias[wcolbase + tx * 4 + 3];
#pragma unroll
  for (int i = 0; i < 4; ++i) {
    int lr = ty * 4 + i;  // local row 0..63
    if (pos0 + lr < chunkEnd) {
      uint2 o;
      o.x = pack_bf16_2(acc[i][0] + b0, acc[i][1] + b1);
      o.y = pack_bf16_2(acc[i][2] + b2, acc[i][3] + b3);
      *(uint2*)&Eb[(long long)(pos0 - chunkStart + lr) * 128 + jblk * 32 + tx * 2] = o;
    }
  }
}

// -------- CSR aggregation + residual + relu (chunked) --------
// one wave per dst node; lane handles channels 2*lane, 2*lane+1
__global__ __launch_bounds__(256) void agg_csr_c(
    const uint* __restrict__ Pb, const uint* __restrict__ Eb,
    const int* __restrict__ rowptr, const uint2* __restrict__ csr,
    int nodeBase, float* __restrict__ h) {
  int wave = threadIdx.x >> 6;
  int lane = threadIdx.x & 63;
  int node = __builtin_amdgcn_readfirstlane(nodeBase + blockIdx.x * 4 + wave);
  int chunkStart = rowptr[nodeBase];
  int row0 = rowptr[node], row1 = rowptr[node + 1];
  const uint* Pd = Pb + (long long)node * 256;
  uint fdu = Pd[lane], sdu = Pd[64 + lane];
  float fd0 = bflo(fdu), fd1 = bfhi(fdu);
  float sd0 = bflo(sdu), sd1 = bfhi(sdu);
  float a0 = 0.f, a1 = 0.f;
  for (int j = row0; j < row1; ++j) {
    uint2 se = csr[j];
    int s = (int)se.x;
    const uint* Ps = Pb + (long long)s * 256;
    uint fsu = Ps[128 + lane], ssu = Ps[192 + lane];
    const uint* Er = Eb + (long long)(j - chunkStart) * 128;
    uint feu = Er[lane], seu = Er[64 + lane];
    float f0 = fd0 + bflo(fsu) + bflo(feu);
    float f1 = fd1 + bfhi(fsu) + bfhi(feu);
    float s0 = sd0 + bflo(ssu) + bflo(seu);
    float s1 = sd1 + bfhi(ssu) + bfhi(seu);
    a0 += sigmoidf_(f0) * softplusf_(s0);
    a1 += sigmoidf_(f1) * softplusf_(s1);
  }
  float2* hp = (float2*)&h[(long long)node * 128 + 2 * lane];
  float2 hv = *hp;
  hv.x = fmaxf(hv.x + a0, 0.f);
  hv.y = fmaxf(hv.y + a1, 0.f);
  *hp = hv;
}

// ---------------- mean pool (atomic) ----------------
__global__ __launch_bounds__(256) void pool_kernel(
    const float* __restrict__ h, const int* __restrict__ batch,
    float* __restrict__ sums, float* __restrict__ cnts) {
  long long i = (long long)blockIdx.x * 256 + threadIdx.x;
  if (i >= (long long)N_NODES * HID) return;
  int n = (int)(i >> 7), c = (int)(i & 127);
  int b = batch[n];
  atomicAdd(&sums[b * HID + c], h[i]);
  if (c == 0) atomicAdd(&cnts[b], 1.f);
}

// ---------------- graph MLP ----------------
__global__ __launch_bounds__(128) void mlpA(
    const float* __restrict__ sums, const float* __restrict__ cnts,
    const float* __restrict__ W1, const float* __restrict__ b1,
    float* __restrict__ g) {
  __shared__ float pl[HID];
  int gr = blockIdx.x, j = threadIdx.x;
  float cnt = fmaxf(cnts[gr], 1.f);
  pl[j] = sums[gr * HID + j] / cnt;
  __syncthreads();
  float acc = b1[j];
#pragma unroll 8
  for (int k = 0; k < HID; ++k) acc = fmaf(pl[k], W1[k * HID + j], acc);
  g[gr * HID + j] = fmaxf(acc, 0.f);
}

__global__ __launch_bounds__(256) void mlpB(
    const float* __restrict__ g, const float* __restrict__ W2,
    const float* __restrict__ b2, float* __restrict__ out) {
  int t = threadIdx.x;
  if (t >= 64 * 3) return;
  int gr = t / 3, o = t % 3;
  float acc = b2[o];
#pragma unroll 8
  for (int k = 0; k < HID; ++k) acc = fmaf(g[gr * HID + k], W2[k * 3 + o], acc);
  out[t] = acc;
}

extern "C" void kernel_launch(void* const* d_in, const int* in_sizes, int n_in,
                              void* d_out, int out_size, void* d_ws, size_t ws_size,
                              hipStream_t stream) {
  const float* x   = (const float*)d_in[0];
  const int*   ei  = (const int*)d_in[1];
  const float* ea  = (const float*)d_in[2];
  const int*   bat = (const int*)d_in[3];
  const float* Wf1 = (const float*)d_in[4];
  const float* bf1 = (const float*)d_in[5];
  const float* Ws1 = (const float*)d_in[6];
  const float* bs1 = (const float*)d_in[7];
  const float* Wp  = (const float*)d_in[8];
  const float* bp  = (const float*)d_in[9];
  const float* Wf2 = (const float*)d_in[10];
  const float* bf2 = (const float*)d_in[11];
  const float* Ws2 = (const float*)d_in[12];
  const float* bs2 = (const float*)d_in[13];
  const float* Wf3 = (const float*)d_in[14];
  const float* bf3 = (const float*)d_in[15];
  const float* Ws3 = (const float*)d_in[16];
  const float* bs3 = (const float*)d_in[17];
  const float* W1  = (const float*)d_in[18];
  const float* b1  = (const float*)d_in[19];
  const float* W2  = (const float*)d_in[20];
  const float* b2  = (const float*)d_in[21];
  float* out = (float*)d_out;

  char* w = (char*)d_ws;
  size_t off = 0;
  auto alloc = [&](size_t bytes) {
    void* p = w + off;
    off += (bytes + 255) & ~(size_t)255;
    return p;
  };
  int*   deg    = (int*)alloc((size_t)N_NODES * 4);
  int*   rowptr = (int*)alloc((size_t)(N_NODES + 1) * 4);
  int*   cur    = (int*)alloc((size_t)N_NODES * 4);
  int*   bsums  = (int*)alloc((size_t)512 * 4);
  uint2* csr    = (uint2*)alloc((size_t)N_EDGES * 8);             // 12.8 MB
  float* agg1   = (float*)alloc((size_t)N_NODES * 3 * 4);         // 1.2 MB
  float* h      = (float*)alloc((size_t)N_NODES * HID * 4);       // 51.2 MB
  uint*  Pb     = (uint*)alloc((size_t)N_NODES * 256 * 4);        // 102.4 MB
  uint*  Eb     = (uint*)alloc((size_t)CHUNK_EDGE_CAP * 128 * 4); // 104.9 MB
  float* sums   = (float*)alloc((size_t)64 * HID * 4);
  float* cnts   = (float*)alloc((size_t)64 * 4);
  float* g      = (float*)alloc((size_t)64 * HID * 4);
  (void)ws_size;  // total ~274 MB

  // ---- CSR build ----
  hipMemsetAsync(deg, 0, (size_t)N_NODES * 4, stream);
  hist_k<<<(N_EDGES + 255) / 256, 256, 0, stream>>>(ei, deg);
  scan1_k<<<SCAN_BLOCKS, 256, 0, stream>>>(deg, rowptr, bsums);
  scan2_k<<<1, 512, 0, stream>>>(bsums);
  scan3_k<<<SCAN_BLOCKS, 256, 0, stream>>>(rowptr, bsums, cur);
  scatter_k<<<(N_EDGES + 255) / 256, 256, 0, stream>>>(ei, cur, csr);

  // ---- conv1 ----
  hipMemsetAsync(agg1, 0, (size_t)N_NODES * 3 * 4, stream);
  conv1_edge<<<(N_EDGES + 255) / 256, 256, 0, stream>>>(x, ei, ea, Wf1, bf1, Ws1, bs1, agg1);
  proj_kernel<<<(N_NODES * HID + 255) / 256, 256, 0, stream>>>(x, agg1, Wp, bp, h);

  dim3 ngrid((N_NODES + BM - 1) / BM, 8);
  dim3 egrid(CHUNK_BLOCKS, 4);
  const int AGG_BLOCKS = NODES_PER_CHUNK / 4;

  // ---- conv2 ----
  node_gemm<<<ngrid, 256, 0, stream>>>(h, Wf2, Ws2, Pb);
  for (int c = 0; c < NCHUNK; ++c) {
    int nb = c * NODES_PER_CHUNK;
    egemm_c<<<egrid, 256, 0, stream>>>(ea, csr, rowptr, Wf2, Ws2, bf2, bs2, nb, Eb);
    agg_csr_c<<<AGG_BLOCKS, 256, 0, stream>>>(Pb, Eb, rowptr, csr, nb, h);
  }

  // ---- conv3 ----
  node_gemm<<<ngrid, 256, 0, stream>>>(h, Wf3, Ws3, Pb);
  for (int c = 0; c < NCHUNK; ++c) {
    int nb = c * NODES_PER_CHUNK;
    egemm_c<<<egrid, 256, 0, stream>>>(ea, csr, rowptr, Wf3, Ws3, bf3, bs3, nb, Eb);
    agg_csr_c<<<AGG_BLOCKS, 256, 0, stream>>>(Pb, Eb, rowptr, csr, nb, h);
  }

  // ---- pool + MLP ----
  hipMemsetAsync(sums, 0, (size_t)(64 * HID + 64) * 4, stream);
  pool_kernel<<<(N_NODES * HID + 255) / 256, 256, 0, stream>>>(h, bat, sums, cnts);
  mlpA<<<64, 128, 0, stream>>>(sums, cnts, W1, b1, g);
  mlpB<<<1, 256, 0, stream>>>(g, W2, b2, out);
}

// Round 5
// 2722.608 us; speedup vs baseline: 1.8507x; 1.8507x over previous
//
#include <hip/hip_runtime.h>
#include <hip/hip_bf16.h>

// CGCNN: 3x CGConv + projection + mean-pool + 2-layer MLP.
// Round 5: fused CSR aggregation — edge transform e@We computed in-register
// inside the per-node wave (no Eb materialization, no chunk loop); node
// transforms Pb in bf16 (102 MB, L3-resident); segmented-reduction pool.
//   f = P_fd[dst] + P_fs[src] + e@Wfe + bf ;  s likewise
//   msg = sigmoid(f) * softplus(s); accumulate in registers per dst wave.

#define N_NODES 100000
#define N_EDGES 1600000
#define HID 128
#define SCAN_BLOCKS 391  // ceil(100000/256)
#define AGGF_BLOCKS 2048

typedef unsigned int uint;

__device__ inline float bflo(uint u) { return __uint_as_float(u << 16); }
__device__ inline float bfhi(uint u) { return __uint_as_float(u & 0xffff0000u); }
__device__ inline uint pack_bf16_2(float a, float b) {
  uint ua = __float_as_uint(a), ub = __float_as_uint(b);
  ua = (ua + 0x7fffu + ((ua >> 16) & 1u)) >> 16;
  ub = (ub + 0x7fffu + ((ub >> 16) & 1u)) >> 16;
  return ua | (ub << 16);
}
__device__ inline float sigmoidf_(float x) {
  return __builtin_amdgcn_rcpf(1.f + __expf(-x));
}
__device__ inline float softplusf_(float x) {
  return fmaxf(x, 0.f) + __logf(1.f + __expf(-fabsf(x)));
}

// ---------------- CSR build ----------------
__global__ __launch_bounds__(256) void hist_k(const int* __restrict__ ei,
                                              int* __restrict__ deg) {
  int e = blockIdx.x * 256 + threadIdx.x;
  if (e >= N_EDGES) return;
  atomicAdd(&deg[ei[N_EDGES + e]], 1);
}

__global__ __launch_bounds__(256) void scan1_k(const int* __restrict__ deg,
                                               int* __restrict__ rowptr,
                                               int* __restrict__ bsums) {
  __shared__ int s[256];
  int i = blockIdx.x * 256 + threadIdx.x;
  int v = (i < N_NODES) ? deg[i] : 0;
  s[threadIdx.x] = v;
  __syncthreads();
  for (int off = 1; off < 256; off <<= 1) {
    int t = (threadIdx.x >= off) ? s[threadIdx.x - off] : 0;
    __syncthreads();
    s[threadIdx.x] += t;
    __syncthreads();
  }
  if (i < N_NODES) rowptr[i] = s[threadIdx.x] - v;  // exclusive
  if (threadIdx.x == 255) bsums[blockIdx.x] = s[255];
}

__global__ __launch_bounds__(512) void scan2_k(int* __restrict__ bsums) {
  __shared__ int s[512];
  int t = threadIdx.x;
  int v = (t < SCAN_BLOCKS) ? bsums[t] : 0;
  s[t] = v;
  __syncthreads();
  for (int off = 1; off < 512; off <<= 1) {
    int x = (t >= off) ? s[t - off] : 0;
    __syncthreads();
    s[t] += x;
    __syncthreads();
  }
  if (t < SCAN_BLOCKS) bsums[t] = s[t] - v;  // exclusive
}

__global__ __launch_bounds__(256) void scan3_k(int* __restrict__ rowptr,
                                               const int* __restrict__ bsums,
                                               int* __restrict__ cur) {
  int i = blockIdx.x * 256 + threadIdx.x;
  if (i < N_NODES) {
    int r = rowptr[i] + bsums[blockIdx.x];
    rowptr[i] = r;
    cur[i] = r;
  }
  if (i == 0) rowptr[N_NODES] = N_EDGES;
}

__global__ __launch_bounds__(256) void scatter_k(const int* __restrict__ ei,
                                                 int* __restrict__ cur,
                                                 uint2* __restrict__ csr) {
  int e = blockIdx.x * 256 + threadIdx.x;
  if (e >= N_EDGES) return;
  int d = ei[N_EDGES + e];
  int pos = atomicAdd(&cur[d], 1);
  csr[pos] = make_uint2((uint)ei[e], (uint)e);
}

// ---------------- conv1 (channels=3) ----------------
__global__ __launch_bounds__(256) void conv1_edge(
    const float* __restrict__ x, const int* __restrict__ ei,
    const float* __restrict__ ea,
    const float* __restrict__ Wf, const float* __restrict__ bf,
    const float* __restrict__ Ws, const float* __restrict__ bs,
    float* __restrict__ agg1) {
  int e = blockIdx.x * 256 + threadIdx.x;
  if (e >= N_EDGES) return;
  int src = ei[e], dst = ei[N_EDGES + e];
  float z[38];
#pragma unroll
  for (int k = 0; k < 3; ++k) z[k] = x[dst * 3 + k];
#pragma unroll
  for (int k = 0; k < 3; ++k) z[3 + k] = x[src * 3 + k];
  const float* er = ea + (long long)e * 32;
#pragma unroll
  for (int k = 0; k < 32; ++k) z[6 + k] = er[k];
#pragma unroll
  for (int c = 0; c < 3; ++c) {
    float f = bf[c], s = bs[c];
#pragma unroll
    for (int k = 0; k < 38; ++k) {
      f = fmaf(z[k], Wf[k * 3 + c], f);
      s = fmaf(z[k], Ws[k * 3 + c], s);
    }
    atomicAdd(&agg1[dst * 3 + c], sigmoidf_(f) * softplusf_(s));
  }
}

// ---------------- projection: h = relu((x+agg1) @ Wp + bp) ----------------
__global__ __launch_bounds__(256) void proj_kernel(
    const float* __restrict__ x, const float* __restrict__ agg1,
    const float* __restrict__ Wp, const float* __restrict__ bp,
    float* __restrict__ h) {
  long long i = (long long)blockIdx.x * 256 + threadIdx.x;
  if (i >= (long long)N_NODES * HID) return;
  int n = (int)(i >> 7), j = (int)(i & 127);
  float v0 = x[n * 3 + 0] + agg1[n * 3 + 0];
  float v1 = x[n * 3 + 1] + agg1[n * 3 + 1];
  float v2 = x[n * 3 + 2] + agg1[n * 3 + 2];
  float acc = bp[j];
  acc = fmaf(v0, Wp[0 * HID + j], acc);
  acc = fmaf(v1, Wp[1 * HID + j], acc);
  acc = fmaf(v2, Wp[2 * HID + j], acc);
  h[i] = fmaxf(acc, 0.f);
}

// ---------------- node transform GEMM -> bf16 Pb ----------------
// Pb[n] (512 bf16): [ f_dst(128) | s_dst(128) | f_src(128) | s_src(128) ]
#define BM 64
#define BK 32
__global__ __launch_bounds__(256) void node_gemm(
    const float* __restrict__ h, const float* __restrict__ Wf,
    const float* __restrict__ Ws, uint* __restrict__ Pb) {
  __shared__ float As[BK][BM + 4];
  __shared__ float Bs[BK][BM + 4];
  int jblk = blockIdx.y;
  int sec = jblk >> 1;
  int colbase = (jblk & 1) * 64;
  const float* W = (sec == 0 || sec == 2) ? Wf : Ws;
  int rowoff = (sec >= 2) ? 128 : 0;
  int m0 = blockIdx.x * BM;
  int tid = threadIdx.x;
  int tx = tid & 15, ty = tid >> 4;
  float acc[4][4] = {};
  for (int k0 = 0; k0 < 128; k0 += BK) {
#pragma unroll
    for (int i = 0; i < 2; ++i) {
      int f = tid + i * 256;
      int r = f >> 3, c4 = (f & 7) * 4;
      float4 v = {0.f, 0.f, 0.f, 0.f};
      int row = m0 + r;
      if (row < N_NODES)
        v = *(const float4*)&h[(long long)row * 128 + k0 + c4];
      As[c4 + 0][r] = v.x; As[c4 + 1][r] = v.y;
      As[c4 + 2][r] = v.z; As[c4 + 3][r] = v.w;
    }
#pragma unroll
    for (int i = 0; i < 2; ++i) {
      int f = tid + i * 256;
      int r = f >> 4, c4 = (f & 15) * 4;
      float4 v = *(const float4*)&W[(long long)(k0 + r + rowoff) * 128 + colbase + c4];
      *(float4*)&Bs[r][c4] = v;
    }
    __syncthreads();
#pragma unroll
    for (int k = 0; k < BK; ++k) {
      float4 a = *(const float4*)&As[k][ty * 4];
      float4 b = *(const float4*)&Bs[k][tx * 4];
      float av[4] = {a.x, a.y, a.z, a.w};
      float bv[4] = {b.x, b.y, b.z, b.w};
#pragma unroll
      for (int i = 0; i < 4; ++i)
#pragma unroll
        for (int j = 0; j < 4; ++j)
          acc[i][j] = fmaf(av[i], bv[j], acc[i][j]);
    }
    __syncthreads();
  }
#pragma unroll
  for (int i = 0; i < 4; ++i) {
    int row = m0 + ty * 4 + i;
    if (row < N_NODES) {
      uint2 o;
      o.x = pack_bf16_2(acc[i][0], acc[i][1]);
      o.y = pack_bf16_2(acc[i][2], acc[i][3]);
      *(uint2*)&Pb[(long long)row * 256 + jblk * 32 + tx * 2] = o;
    }
  }
}

// -------- fused CSR aggregation: edge transform in-register --------
// one wave per dst node (grid-stride); lane owns channels 2*lane, 2*lane+1.
// Edge weights (32 k x 2 ch x {f,s}) live in VGPRs, loaded once per wave.
__global__ __launch_bounds__(256, 2) void agg_fused(
    const uint* __restrict__ Pb, const float* __restrict__ ea,
    const float* __restrict__ Wf, const float* __restrict__ Ws,
    const float* __restrict__ bf, const float* __restrict__ bs,
    const int* __restrict__ rowptr, const uint2* __restrict__ csr,
    float* __restrict__ h) {
  int wave = threadIdx.x >> 6;
  int lane = threadIdx.x & 63;
  int c0 = 2 * lane;
  float wf0[32], wf1[32], ws0[32], ws1[32];
#pragma unroll
  for (int k = 0; k < 32; ++k) {
    float2 wfv = *(const float2*)&Wf[(256 + k) * HID + c0];
    float2 wsv = *(const float2*)&Ws[(256 + k) * HID + c0];
    wf0[k] = wfv.x; wf1[k] = wfv.y;
    ws0[k] = wsv.x; ws1[k] = wsv.y;
  }
  float bfc0 = bf[c0], bfc1 = bf[c0 + 1];
  float bsc0 = bs[c0], bsc1 = bs[c0 + 1];
  for (int node = blockIdx.x * 4 + wave; node < N_NODES; node += gridDim.x * 4) {
    int row0 = rowptr[node], row1 = rowptr[node + 1];
    const uint* Pd = Pb + (long long)node * 256;
    uint fdu = Pd[lane], sdu = Pd[64 + lane];
    float fd0 = bflo(fdu) + bfc0, fd1 = bfhi(fdu) + bfc1;
    float sd0 = bflo(sdu) + bsc0, sd1 = bfhi(sdu) + bsc1;
    float a0 = 0.f, a1 = 0.f;
    for (int j = row0; j < row1; ++j) {
      uint2 se = csr[j];
      int s = __builtin_amdgcn_readfirstlane((int)se.x);
      int e = __builtin_amdgcn_readfirstlane((int)se.y);
      const float* er = ea + (long long)e * 32;
      float ef0 = 0.f, ef1 = 0.f, es0 = 0.f, es1 = 0.f;
#pragma unroll
      for (int k = 0; k < 32; ++k) {
        float ev = er[k];
        ef0 = fmaf(ev, wf0[k], ef0);
        ef1 = fmaf(ev, wf1[k], ef1);
        es0 = fmaf(ev, ws0[k], es0);
        es1 = fmaf(ev, ws1[k], es1);
      }
      const uint* Ps = Pb + (long long)s * 256;
      uint fsu = Ps[128 + lane], ssu = Ps[192 + lane];
      float f0 = fd0 + bflo(fsu) + ef0;
      float f1 = fd1 + bfhi(fsu) + ef1;
      float s0 = sd0 + bflo(ssu) + es0;
      float s1 = sd1 + bfhi(ssu) + es1;
      a0 += sigmoidf_(f0) * softplusf_(s0);
      a1 += sigmoidf_(f1) * softplusf_(s1);
    }
    float2* hp = (float2*)&h[(long long)node * HID + c0];
    float2 hv = *hp;
    hv.x = fmaxf(hv.x + a0, 0.f);
    hv.y = fmaxf(hv.y + a1, 0.f);
    *hp = hv;
  }
}

// -------- segmented mean pool (batch sorted; ~2 flushes per block) --------
#define POOL_NODES 128
__global__ __launch_bounds__(128) void pool2(
    const float* __restrict__ h, const int* __restrict__ batch,
    float* __restrict__ sums, float* __restrict__ cnts) {
  int n0 = blockIdx.x * POOL_NODES;
  if (n0 >= N_NODES) return;
  int t = threadIdx.x;
  int nEnd = n0 + POOL_NODES;
  if (nEnd > N_NODES) nEnd = N_NODES;
  float acc = 0.f;
  int bcur = batch[n0];
  int cnt = 0;
  for (int n = n0; n < nEnd; ++n) {
    int b = batch[n];
    if (b != bcur) {
      atomicAdd(&sums[bcur * HID + t], acc);
      if (t == 0) atomicAdd(&cnts[bcur], (float)cnt);
      acc = 0.f; cnt = 0; bcur = b;
    }
    acc += h[(long long)n * HID + t];
    ++cnt;
  }
  atomicAdd(&sums[bcur * HID + t], acc);
  if (t == 0) atomicAdd(&cnts[bcur], (float)cnt);
}

// ---------------- graph MLP ----------------
__global__ __launch_bounds__(128) void mlpA(
    const float* __restrict__ sums, const float* __restrict__ cnts,
    const float* __restrict__ W1, const float* __restrict__ b1,
    float* __restrict__ g) {
  __shared__ float pl[HID];
  int gr = blockIdx.x, j = threadIdx.x;
  float cnt = fmaxf(cnts[gr], 1.f);
  pl[j] = sums[gr * HID + j] / cnt;
  __syncthreads();
  float acc = b1[j];
#pragma unroll 8
  for (int k = 0; k < HID; ++k) acc = fmaf(pl[k], W1[k * HID + j], acc);
  g[gr * HID + j] = fmaxf(acc, 0.f);
}

__global__ __launch_bounds__(256) void mlpB(
    const float* __restrict__ g, const float* __restrict__ W2,
    const float* __restrict__ b2, float* __restrict__ out) {
  int t = threadIdx.x;
  if (t >= 64 * 3) return;
  int gr = t / 3, o = t % 3;
  float acc = b2[o];
#pragma unroll 8
  for (int k = 0; k < HID; ++k) acc = fmaf(g[gr * HID + k], W2[k * 3 + o], acc);
  out[t] = acc;
}

extern "C" void kernel_launch(void* const* d_in, const int* in_sizes, int n_in,
                              void* d_out, int out_size, void* d_ws, size_t ws_size,
                              hipStream_t stream) {
  const float* x   = (const float*)d_in[0];
  const int*   ei  = (const int*)d_in[1];
  const float* ea  = (const float*)d_in[2];
  const int*   bat = (const int*)d_in[3];
  const float* Wf1 = (const float*)d_in[4];
  const float* bf1 = (const float*)d_in[5];
  const float* Ws1 = (const float*)d_in[6];
  const float* bs1 = (const float*)d_in[7];
  const float* Wp  = (const float*)d_in[8];
  const float* bp  = (const float*)d_in[9];
  const float* Wf2 = (const float*)d_in[10];
  const float* bf2 = (const float*)d_in[11];
  const float* Ws2 = (const float*)d_in[12];
  const float* bs2 = (const float*)d_in[13];
  const float* Wf3 = (const float*)d_in[14];
  const float* bf3 = (const float*)d_in[15];
  const float* Ws3 = (const float*)d_in[16];
  const float* bs3 = (const float*)d_in[17];
  const float* W1  = (const float*)d_in[18];
  const float* b1  = (const float*)d_in[19];
  const float* W2  = (const float*)d_in[20];
  const float* b2  = (const float*)d_in[21];
  float* out = (float*)d_out;

  char* w = (char*)d_ws;
  size_t off = 0;
  auto alloc = [&](size_t bytes) {
    void* p = w + off;
    off += (bytes + 255) & ~(size_t)255;
    return p;
  };
  int*   deg    = (int*)alloc((size_t)N_NODES * 4);
  int*   rowptr = (int*)alloc((size_t)(N_NODES + 1) * 4);
  int*   cur    = (int*)alloc((size_t)N_NODES * 4);
  int*   bsums  = (int*)alloc((size_t)512 * 4);
  uint2* csr    = (uint2*)alloc((size_t)N_EDGES * 8);        // 12.8 MB
  float* agg1   = (float*)alloc((size_t)N_NODES * 3 * 4);    // 1.2 MB
  float* h      = (float*)alloc((size_t)N_NODES * HID * 4);  // 51.2 MB
  uint*  Pb     = (uint*)alloc((size_t)N_NODES * 256 * 4);   // 102.4 MB
  float* sums   = (float*)alloc((size_t)64 * HID * 4);
  float* cnts   = (float*)alloc((size_t)64 * 4);
  float* g      = (float*)alloc((size_t)64 * HID * 4);
  (void)ws_size;  // total ~170 MB

  // ---- CSR build ----
  hipMemsetAsync(deg, 0, (size_t)N_NODES * 4, stream);
  hist_k<<<(N_EDGES + 255) / 256, 256, 0, stream>>>(ei, deg);
  scan1_k<<<SCAN_BLOCKS, 256, 0, stream>>>(deg, rowptr, bsums);
  scan2_k<<<1, 512, 0, stream>>>(bsums);
  scan3_k<<<SCAN_BLOCKS, 256, 0, stream>>>(rowptr, bsums, cur);
  scatter_k<<<(N_EDGES + 255) / 256, 256, 0, stream>>>(ei, cur, csr);

  // ---- conv1 ----
  hipMemsetAsync(agg1, 0, (size_t)N_NODES * 3 * 4, stream);
  conv1_edge<<<(N_EDGES + 255) / 256, 256, 0, stream>>>(x, ei, ea, Wf1, bf1, Ws1, bs1, agg1);
  proj_kernel<<<(N_NODES * HID + 255) / 256, 256, 0, stream>>>(x, agg1, Wp, bp, h);

  dim3 ngrid((N_NODES + BM - 1) / BM, 8);

  // ---- conv2 ----
  node_gemm<<<ngrid, 256, 0, stream>>>(h, Wf2, Ws2, Pb);
  agg_fused<<<AGGF_BLOCKS, 256, 0, stream>>>(Pb, ea, Wf2, Ws2, bf2, bs2, rowptr, csr, h);

  // ---- conv3 ----
  node_gemm<<<ngrid, 256, 0, stream>>>(h, Wf3, Ws3, Pb);
  agg_fused<<<AGGF_BLOCKS, 256, 0, stream>>>(Pb, ea, Wf3, Ws3, bf3, bs3, rowptr, csr, h);

  // ---- pool + MLP ----
  hipMemsetAsync(sums, 0, (size_t)(64 * HID + 64) * 4, stream);
  pool2<<<(N_NODES + POOL_NODES - 1) / POOL_NODES, POOL_NODES, 0, stream>>>(h, bat, sums, cnts);
  mlpA<<<64, 128, 0, stream>>>(sums, cnts, W1, b1, g);
  mlpB<<<1, 256, 0, stream>>>(g, W2, b2, out);
}

// Round 6
// 2337.413 us; speedup vs baseline: 2.1557x; 1.1648x over previous
//
#include <hip/hip_runtime.h>
#include <hip/hip_bf16.h>

// CGCNN: 3x CGConv + projection + mean-pool + 2-layer MLP.
// Round 6: agg_fused v2 — 2 waves per node (64 ch each) so the per-wave
// edge-weight cache is 64 VGPRs (below the remat threshold that bit Round 5
// at VGPR=80), 2-edge inner groups for ILP, scalar (SMEM) ea loads.
//   f = P_fd[dst] + P_fs[src] + e@Wfe + bf ;  s likewise
//   msg = sigmoid(f) * softplus(s); accumulate in registers per dst wave.

#define N_NODES 100000
#define N_EDGES 1600000
#define HID 128
#define SCAN_BLOCKS 391  // ceil(100000/256)
#define AGGF_BLOCKS 8192

typedef unsigned int uint;

__device__ inline float bflo(uint u) { return __uint_as_float(u << 16); }
__device__ inline float bfhi(uint u) { return __uint_as_float(u & 0xffff0000u); }
// parity-select: shamt = 16 for low half (even ch), 0 for high half (odd ch)
__device__ inline float bfsel(uint u, uint shamt) {
  return __uint_as_float((u << shamt) & 0xffff0000u);
}
__device__ inline uint pack_bf16_2(float a, float b) {
  uint ua = __float_as_uint(a), ub = __float_as_uint(b);
  ua = (ua + 0x7fffu + ((ua >> 16) & 1u)) >> 16;
  ub = (ub + 0x7fffu + ((ub >> 16) & 1u)) >> 16;
  return ua | (ub << 16);
}
__device__ inline float sigmoidf_(float x) {
  return __builtin_amdgcn_rcpf(1.f + __expf(-x));
}
__device__ inline float softplusf_(float x) {
  return fmaxf(x, 0.f) + __logf(1.f + __expf(-fabsf(x)));
}

// ---------------- CSR build ----------------
__global__ __launch_bounds__(256) void hist_k(const int* __restrict__ ei,
                                              int* __restrict__ deg) {
  int e = blockIdx.x * 256 + threadIdx.x;
  if (e >= N_EDGES) return;
  atomicAdd(&deg[ei[N_EDGES + e]], 1);
}

__global__ __launch_bounds__(256) void scan1_k(const int* __restrict__ deg,
                                               int* __restrict__ rowptr,
                                               int* __restrict__ bsums) {
  __shared__ int s[256];
  int i = blockIdx.x * 256 + threadIdx.x;
  int v = (i < N_NODES) ? deg[i] : 0;
  s[threadIdx.x] = v;
  __syncthreads();
  for (int off = 1; off < 256; off <<= 1) {
    int t = (threadIdx.x >= off) ? s[threadIdx.x - off] : 0;
    __syncthreads();
    s[threadIdx.x] += t;
    __syncthreads();
  }
  if (i < N_NODES) rowptr[i] = s[threadIdx.x] - v;  // exclusive
  if (threadIdx.x == 255) bsums[blockIdx.x] = s[255];
}

__global__ __launch_bounds__(512) void scan2_k(int* __restrict__ bsums) {
  __shared__ int s[512];
  int t = threadIdx.x;
  int v = (t < SCAN_BLOCKS) ? bsums[t] : 0;
  s[t] = v;
  __syncthreads();
  for (int off = 1; off < 512; off <<= 1) {
    int x = (t >= off) ? s[t - off] : 0;
    __syncthreads();
    s[t] += x;
    __syncthreads();
  }
  if (t < SCAN_BLOCKS) bsums[t] = s[t] - v;  // exclusive
}

__global__ __launch_bounds__(256) void scan3_k(int* __restrict__ rowptr,
                                               const int* __restrict__ bsums,
                                               int* __restrict__ cur) {
  int i = blockIdx.x * 256 + threadIdx.x;
  if (i < N_NODES) {
    int r = rowptr[i] + bsums[blockIdx.x];
    rowptr[i] = r;
    cur[i] = r;
  }
  if (i == 0) rowptr[N_NODES] = N_EDGES;
}

__global__ __launch_bounds__(256) void scatter_k(const int* __restrict__ ei,
                                                 int* __restrict__ cur,
                                                 uint2* __restrict__ csr) {
  int e = blockIdx.x * 256 + threadIdx.x;
  if (e >= N_EDGES) return;
  int d = ei[N_EDGES + e];
  int pos = atomicAdd(&cur[d], 1);
  csr[pos] = make_uint2((uint)ei[e], (uint)e);
}

// ---------------- conv1 (channels=3) ----------------
__global__ __launch_bounds__(256) void conv1_edge(
    const float* __restrict__ x, const int* __restrict__ ei,
    const float* __restrict__ ea,
    const float* __restrict__ Wf, const float* __restrict__ bf,
    const float* __restrict__ Ws, const float* __restrict__ bs,
    float* __restrict__ agg1) {
  int e = blockIdx.x * 256 + threadIdx.x;
  if (e >= N_EDGES) return;
  int src = ei[e], dst = ei[N_EDGES + e];
  float z[38];
#pragma unroll
  for (int k = 0; k < 3; ++k) z[k] = x[dst * 3 + k];
#pragma unroll
  for (int k = 0; k < 3; ++k) z[3 + k] = x[src * 3 + k];
  const float4* er4 = (const float4*)(ea + (long long)e * 32);
#pragma unroll
  for (int k = 0; k < 8; ++k) {
    float4 v = er4[k];
    z[6 + 4 * k + 0] = v.x;
    z[6 + 4 * k + 1] = v.y;
    z[6 + 4 * k + 2] = v.z;
    z[6 + 4 * k + 3] = v.w;
  }
#pragma unroll
  for (int c = 0; c < 3; ++c) {
    float f = bf[c], s = bs[c];
#pragma unroll
    for (int k = 0; k < 38; ++k) {
      f = fmaf(z[k], Wf[k * 3 + c], f);
      s = fmaf(z[k], Ws[k * 3 + c], s);
    }
    atomicAdd(&agg1[dst * 3 + c], sigmoidf_(f) * softplusf_(s));
  }
}

// ---------------- projection: h = relu((x+agg1) @ Wp + bp) ----------------
__global__ __launch_bounds__(256) void proj_kernel(
    const float* __restrict__ x, const float* __restrict__ agg1,
    const float* __restrict__ Wp, const float* __restrict__ bp,
    float* __restrict__ h) {
  long long i = (long long)blockIdx.x * 256 + threadIdx.x;
  if (i >= (long long)N_NODES * HID) return;
  int n = (int)(i >> 7), j = (int)(i & 127);
  float v0 = x[n * 3 + 0] + agg1[n * 3 + 0];
  float v1 = x[n * 3 + 1] + agg1[n * 3 + 1];
  float v2 = x[n * 3 + 2] + agg1[n * 3 + 2];
  float acc = bp[j];
  acc = fmaf(v0, Wp[0 * HID + j], acc);
  acc = fmaf(v1, Wp[1 * HID + j], acc);
  acc = fmaf(v2, Wp[2 * HID + j], acc);
  h[i] = fmaxf(acc, 0.f);
}

// ---------------- node transform GEMM -> bf16 Pb ----------------
// Pb[n] (512 bf16): [ f_dst(128) | s_dst(128) | f_src(128) | s_src(128) ]
#define BM 64
#define BK 32
__global__ __launch_bounds__(256) void node_gemm(
    const float* __restrict__ h, const float* __restrict__ Wf,
    const float* __restrict__ Ws, uint* __restrict__ Pb) {
  __shared__ float As[BK][BM + 4];
  __shared__ float Bs[BK][BM + 4];
  int jblk = blockIdx.y;
  int sec = jblk >> 1;
  int colbase = (jblk & 1) * 64;
  const float* W = (sec == 0 || sec == 2) ? Wf : Ws;
  int rowoff = (sec >= 2) ? 128 : 0;
  int m0 = blockIdx.x * BM;
  int tid = threadIdx.x;
  int tx = tid & 15, ty = tid >> 4;
  float acc[4][4] = {};
  for (int k0 = 0; k0 < 128; k0 += BK) {
#pragma unroll
    for (int i = 0; i < 2; ++i) {
      int f = tid + i * 256;
      int r = f >> 3, c4 = (f & 7) * 4;
      float4 v = {0.f, 0.f, 0.f, 0.f};
      int row = m0 + r;
      if (row < N_NODES)
        v = *(const float4*)&h[(long long)row * 128 + k0 + c4];
      As[c4 + 0][r] = v.x; As[c4 + 1][r] = v.y;
      As[c4 + 2][r] = v.z; As[c4 + 3][r] = v.w;
    }
#pragma unroll
    for (int i = 0; i < 2; ++i) {
      int f = tid + i * 256;
      int r = f >> 4, c4 = (f & 15) * 4;
      float4 v = *(const float4*)&W[(long long)(k0 + r + rowoff) * 128 + colbase + c4];
      *(float4*)&Bs[r][c4] = v;
    }
    __syncthreads();
#pragma unroll
    for (int k = 0; k < BK; ++k) {
      float4 a = *(const float4*)&As[k][ty * 4];
      float4 b = *(const float4*)&Bs[k][tx * 4];
      float av[4] = {a.x, a.y, a.z, a.w};
      float bv[4] = {b.x, b.y, b.z, b.w};
#pragma unroll
      for (int i = 0; i < 4; ++i)
#pragma unroll
        for (int j = 0; j < 4; ++j)
          acc[i][j] = fmaf(av[i], bv[j], acc[i][j]);
    }
    __syncthreads();
  }
#pragma unroll
  for (int i = 0; i < 4; ++i) {
    int row = m0 + ty * 4 + i;
    if (row < N_NODES) {
      uint2 o;
      o.x = pack_bf16_2(acc[i][0], acc[i][1]);
      o.y = pack_bf16_2(acc[i][2], acc[i][3]);
      *(uint2*)&Pb[(long long)row * 256 + jblk * 32 + tx * 2] = o;
    }
  }
}

// -------- fused CSR aggregation v2: 2 waves/node, 64 ch per wave --------
// Weight cache = 64 floats/wave (below remat threshold). 2-edge groups.
__global__ __launch_bounds__(256, 4) void agg_fused(
    const uint* __restrict__ Pb, const float* __restrict__ ea,
    const float* __restrict__ Wf, const float* __restrict__ Ws,
    const float* __restrict__ bf, const float* __restrict__ bs,
    const int* __restrict__ rowptr, const uint2* __restrict__ csr,
    float* __restrict__ h) {
  int wave = threadIdx.x >> 6;
  int lane = threadIdx.x & 63;
  int c = ((wave & 1) << 6) + lane;  // channel 0..127
  int nodeSlot = wave >> 1;          // 0..1
  float wf[32], ws[32];
#pragma unroll
  for (int k = 0; k < 32; ++k) {
    wf[k] = Wf[(256 + k) * HID + c];
    ws[k] = Ws[(256 + k) * HID + c];
  }
  float bfc = bf[c], bsc = bs[c];
  int dw = c >> 1;                       // dword index within 64-dword region
  uint shamt = (c & 1) ? 0u : 16u;       // bf16 half select
  for (int node = blockIdx.x * 2 + nodeSlot; node < N_NODES;
       node += gridDim.x * 2) {
    int row0 = rowptr[node], row1 = rowptr[node + 1];
    const uint* Pd = Pb + (long long)node * 256;
    uint fdu = Pd[dw], sdu = Pd[64 + dw];
    float fd = bfsel(fdu, shamt) + bfc;
    float sd = bfsel(sdu, shamt) + bsc;
    float a = 0.f;
    int j = row0;
    for (; j + 1 < row1; j += 2) {
      uint2 m0 = csr[j], m1 = csr[j + 1];
      int sA = __builtin_amdgcn_readfirstlane((int)m0.x);
      int eA = __builtin_amdgcn_readfirstlane((int)m0.y);
      int sB = __builtin_amdgcn_readfirstlane((int)m1.x);
      int eB = __builtin_amdgcn_readfirstlane((int)m1.y);
      const float* erA = ea + (long long)eA * 32;
      const float* erB = ea + (long long)eB * 32;
      const uint* PsA = Pb + (long long)sA * 256;
      const uint* PsB = Pb + (long long)sB * 256;
      uint fsuA = PsA[128 + dw], ssuA = PsA[192 + dw];
      uint fsuB = PsB[128 + dw], ssuB = PsB[192 + dw];
      float efA = 0.f, esA = 0.f, efB = 0.f, esB = 0.f;
#pragma unroll
      for (int k = 0; k < 32; ++k) {
        float evA = erA[k], evB = erB[k];
        efA = fmaf(evA, wf[k], efA);
        esA = fmaf(evA, ws[k], esA);
        efB = fmaf(evB, wf[k], efB);
        esB = fmaf(evB, ws[k], esB);
      }
      float fA = fd + bfsel(fsuA, shamt) + efA;
      float gA = sd + bfsel(ssuA, shamt) + esA;
      float fB = fd + bfsel(fsuB, shamt) + efB;
      float gB = sd + bfsel(ssuB, shamt) + esB;
      a += sigmoidf_(fA) * softplusf_(gA);
      a += sigmoidf_(fB) * softplusf_(gB);
    }
    if (j < row1) {
      uint2 m0 = csr[j];
      int sA = __builtin_amdgcn_readfirstlane((int)m0.x);
      int eA = __builtin_amdgcn_readfirstlane((int)m0.y);
      const float* erA = ea + (long long)eA * 32;
      const uint* PsA = Pb + (long long)sA * 256;
      uint fsuA = PsA[128 + dw], ssuA = PsA[192 + dw];
      float efA = 0.f, esA = 0.f;
#pragma unroll
      for (int k = 0; k < 32; ++k) {
        float evA = erA[k];
        efA = fmaf(evA, wf[k], efA);
        esA = fmaf(evA, ws[k], esA);
      }
      float fA = fd + bfsel(fsuA, shamt) + efA;
      float gA = sd + bfsel(ssuA, shamt) + esA;
      a += sigmoidf_(fA) * softplusf_(gA);
    }
    float* hp = &h[(long long)node * HID + c];
    *hp = fmaxf(*hp + a, 0.f);
  }
}

// -------- segmented mean pool (batch sorted; ~2 flushes per block) --------
#define POOL_NODES 128
__global__ __launch_bounds__(128) void pool2(
    const float* __restrict__ h, const int* __restrict__ batch,
    float* __restrict__ sums, float* __restrict__ cnts) {
  int n0 = blockIdx.x * POOL_NODES;
  if (n0 >= N_NODES) return;
  int t = threadIdx.x;
  int nEnd = n0 + POOL_NODES;
  if (nEnd > N_NODES) nEnd = N_NODES;
  float acc = 0.f;
  int bcur = batch[n0];
  int cnt = 0;
  for (int n = n0; n < nEnd; ++n) {
    int b = batch[n];
    if (b != bcur) {
      atomicAdd(&sums[bcur * HID + t], acc);
      if (t == 0) atomicAdd(&cnts[bcur], (float)cnt);
      acc = 0.f; cnt = 0; bcur = b;
    }
    acc += h[(long long)n * HID + t];
    ++cnt;
  }
  atomicAdd(&sums[bcur * HID + t], acc);
  if (t == 0) atomicAdd(&cnts[bcur], (float)cnt);
}

// ---------------- graph MLP ----------------
__global__ __launch_bounds__(128) void mlpA(
    const float* __restrict__ sums, const float* __restrict__ cnts,
    const float* __restrict__ W1, const float* __restrict__ b1,
    float* __restrict__ g) {
  __shared__ float pl[HID];
  int gr = blockIdx.x, j = threadIdx.x;
  float cnt = fmaxf(cnts[gr], 1.f);
  pl[j] = sums[gr * HID + j] / cnt;
  __syncthreads();
  float acc = b1[j];
#pragma unroll 8
  for (int k = 0; k < HID; ++k) acc = fmaf(pl[k], W1[k * HID + j], acc);
  g[gr * HID + j] = fmaxf(acc, 0.f);
}

__global__ __launch_bounds__(256) void mlpB(
    const float* __restrict__ g, const float* __restrict__ W2,
    const float* __restrict__ b2, float* __restrict__ out) {
  int t = threadIdx.x;
  if (t >= 64 * 3) return;
  int gr = t / 3, o = t % 3;
  float acc = b2[o];
#pragma unroll 8
  for (int k = 0; k < HID; ++k) acc = fmaf(g[gr * HID + k], W2[k * 3 + o], acc);
  out[t] = acc;
}

extern "C" void kernel_launch(void* const* d_in, const int* in_sizes, int n_in,
                              void* d_out, int out_size, void* d_ws, size_t ws_size,
                              hipStream_t stream) {
  const float* x   = (const float*)d_in[0];
  const int*   ei  = (const int*)d_in[1];
  const float* ea  = (const float*)d_in[2];
  const int*   bat = (const int*)d_in[3];
  const float* Wf1 = (const float*)d_in[4];
  const float* bf1 = (const float*)d_in[5];
  const float* Ws1 = (const float*)d_in[6];
  const float* bs1 = (const float*)d_in[7];
  const float* Wp  = (const float*)d_in[8];
  const float* bp  = (const float*)d_in[9];
  const float* Wf2 = (const float*)d_in[10];
  const float* bf2 = (const float*)d_in[11];
  const float* Ws2 = (const float*)d_in[12];
  const float* bs2 = (const float*)d_in[13];
  const float* Wf3 = (const float*)d_in[14];
  const float* bf3 = (const float*)d_in[15];
  const float* Ws3 = (const float*)d_in[16];
  const float* bs3 = (const float*)d_in[17];
  const float* W1  = (const float*)d_in[18];
  const float* b1  = (const float*)d_in[19];
  const float* W2  = (const float*)d_in[20];
  const float* b2  = (const float*)d_in[21];
  float* out = (float*)d_out;

  char* w = (char*)d_ws;
  size_t off = 0;
  auto alloc = [&](size_t bytes) {
    void* p = w + off;
    off += (bytes + 255) & ~(size_t)255;
    return p;
  };
  int*   deg    = (int*)alloc((size_t)N_NODES * 4);
  int*   rowptr = (int*)alloc((size_t)(N_NODES + 1) * 4);
  int*   cur    = (int*)alloc((size_t)N_NODES * 4);
  int*   bsums  = (int*)alloc((size_t)512 * 4);
  uint2* csr    = (uint2*)alloc((size_t)N_EDGES * 8);        // 12.8 MB
  float* agg1   = (float*)alloc((size_t)N_NODES * 3 * 4);    // 1.2 MB
  float* h      = (float*)alloc((size_t)N_NODES * HID * 4);  // 51.2 MB
  uint*  Pb     = (uint*)alloc((size_t)N_NODES * 256 * 4);   // 102.4 MB
  float* sums   = (float*)alloc((size_t)64 * HID * 4);
  float* cnts   = (float*)alloc((size_t)64 * 4);
  float* g      = (float*)alloc((size_t)64 * HID * 4);
  (void)ws_size;  // total ~170 MB

  // ---- CSR build ----
  hipMemsetAsync(deg, 0, (size_t)N_NODES * 4, stream);
  hist_k<<<(N_EDGES + 255) / 256, 256, 0, stream>>>(ei, deg);
  scan1_k<<<SCAN_BLOCKS, 256, 0, stream>>>(deg, rowptr, bsums);
  scan2_k<<<1, 512, 0, stream>>>(bsums);
  scan3_k<<<SCAN_BLOCKS, 256, 0, stream>>>(rowptr, bsums, cur);
  scatter_k<<<(N_EDGES + 255) / 256, 256, 0, stream>>>(ei, cur, csr);

  // ---- conv1 ----
  hipMemsetAsync(agg1, 0, (size_t)N_NODES * 3 * 4, stream);
  conv1_edge<<<(N_EDGES + 255) / 256, 256, 0, stream>>>(x, ei, ea, Wf1, bf1, Ws1, bs1, agg1);
  proj_kernel<<<(N_NODES * HID + 255) / 256, 256, 0, stream>>>(x, agg1, Wp, bp, h);

  dim3 ngrid((N_NODES + BM - 1) / BM, 8);

  // ---- conv2 ----
  node_gemm<<<ngrid, 256, 0, stream>>>(h, Wf2, Ws2, Pb);
  agg_fused<<<AGGF_BLOCKS, 256, 0, stream>>>(Pb, ea, Wf2, Ws2, bf2, bs2, rowptr, csr, h);

  // ---- conv3 ----
  node_gemm<<<ngrid, 256, 0, stream>>>(h, Wf3, Ws3, Pb);
  agg_fused<<<AGGF_BLOCKS, 256, 0, stream>>>(Pb, ea, Wf3, Ws3, bf3, bs3, rowptr, csr, h);

  // ---- pool + MLP ----
  hipMemsetAsync(sums, 0, (size_t)(64 * HID + 64) * 4, stream);
  pool2<<<(N_NODES + POOL_NODES - 1) / POOL_NODES, POOL_NODES, 0, stream>>>(h, bat, sums, cnts);
  mlpA<<<64, 128, 0, stream>>>(sums, cnts, W1, b1, g);
  mlpB<<<1, 256, 0, stream>>>(g, W2, b2, out);
}